// Round 9
// baseline (879.404 us; speedup 1.0000x reference)
//
#include <hip/hip_runtime.h>
#include <hip/hip_bf16.h>

#define TOKENS 2048
#define HDIM   2560
#define NEXP   16
#define IDIM   1664
#define ISDIM  3328
#define NPAIR  (TOKENS*2)

typedef float  f32x4   __attribute__((ext_vector_type(4)));
typedef __bf16 bf16x8  __attribute__((ext_vector_type(8)));
typedef short  short8v __attribute__((ext_vector_type(8)));

#define GLDS16(g, l) __builtin_amdgcn_global_load_lds( \
    (const __attribute__((address_space(1))) unsigned int*)(g), \
    (__attribute__((address_space(3))) unsigned int*)(l), 16, 0, 0)

#define VMCNT(n) asm volatile("s_waitcnt vmcnt(" #n ")" ::: "memory")
#define LGKM_BAR() do { \
    asm volatile("s_waitcnt lgkmcnt(0)" ::: "memory"); \
    __builtin_amdgcn_sched_barrier(0); \
    __builtin_amdgcn_s_barrier(); \
    __builtin_amdgcn_sched_barrier(0); \
  } while (0)
#define PLAIN_BAR() do { \
    __builtin_amdgcn_sched_barrier(0); \
    __builtin_amdgcn_s_barrier(); \
    __builtin_amdgcn_sched_barrier(0); \
  } while (0)

__device__ __forceinline__ short f2bf(float f) {
  unsigned u = __builtin_bit_cast(unsigned, f);
  u += 0x7FFFu + ((u >> 16) & 1u);          // RNE to bf16
  return (short)(u >> 16);
}

// ---------------- router: fp32 logits, softmax-top2-renorm == sigmoid(l0-l1)
__global__ void router_kernel(const float* __restrict__ x, const float* __restrict__ rw,
                              int* __restrict__ counts, int* __restrict__ tidx,
                              float* __restrict__ tw) {
  const int t = blockIdx.x;
  const int lane = threadIdx.x;
  float acc[NEXP];
#pragma unroll
  for (int e = 0; e < NEXP; ++e) acc[e] = 0.f;
  const float* xr = x + (size_t)t * HDIM;
  for (int k = lane; k < HDIM; k += 64) {
    float xv = xr[k];
#pragma unroll
    for (int e = 0; e < NEXP; ++e) acc[e] += xv * rw[e * HDIM + k];
  }
#pragma unroll
  for (int e = 0; e < NEXP; ++e) {
#pragma unroll
    for (int o = 32; o > 0; o >>= 1) acc[e] += __shfl_down(acc[e], o);
  }
  if (lane == 0) {
    int i0 = 0; float v0 = acc[0];
#pragma unroll
    for (int e = 1; e < NEXP; ++e) if (acc[e] > v0) { v0 = acc[e]; i0 = e; }
    int i1 = -1; float v1 = -3.4e38f;
#pragma unroll
    for (int e = 0; e < NEXP; ++e) if (e != i0 && acc[e] > v1) { v1 = acc[e]; i1 = e; }
    float w0 = 1.f / (1.f + expf(v1 - v0));
    tidx[t * 2] = i0; tidx[t * 2 + 1] = i1;
    tw[t * 2] = w0;   tw[t * 2 + 1] = 1.f - w0;
    atomicAdd(&counts[i0], 1);
    atomicAdd(&counts[i1], 1);
  }
}

__global__ void scan_kernel(const int* __restrict__ counts, int* __restrict__ offsets) {
  if (threadIdx.x == 0) {
    int a = 0;
    for (int e = 0; e < NEXP; ++e) { offsets[e] = a; a += counts[e]; }
  }
}

// ---------------- bucket pairs + gather bf16 activations
__global__ void gather_kernel(const float* __restrict__ x, const int* __restrict__ tidx,
                              const float* __restrict__ tw, const int* __restrict__ offsets,
                              int* __restrict__ slotc, int* __restrict__ pairpos,
                              float* __restrict__ wrow, short* __restrict__ xb,
                              short* __restrict__ xg) {
  const int t = blockIdx.x, tid = threadIdx.x;
  __shared__ int grs[2];
  if (tid < 2) {
    int e = tidx[t * 2 + tid];
    int slot = atomicAdd(&slotc[e], 1);
    int g = offsets[e] + slot;
    grs[tid] = g;
    pairpos[t * 2 + tid] = g;
    wrow[g] = tw[t * 2 + tid];
  }
  __syncthreads();
  const int g0 = grs[0], g1 = grs[1];
  const float* xr = x + (size_t)t * HDIM;
#pragma unroll
  for (int i = 0; i < HDIM / 256; ++i) {
    int k = tid + i * 256;
    short v = f2bf(xr[k]);
    xb[(size_t)t * HDIM + k] = v;
    xg[(size_t)g0 * HDIM + k] = v;
    xg[(size_t)g1 * HDIM + k] = v;
  }
}

// ---------------- weight convert: fp32 [K][N] (N-contig) -> bf16 tile-linear,
// pre-swizzled so a linear global_load_lds produces LDS [BN][32] with 16B-unit
// index  n*4 + (koct ^ ((n>>1)&3))  -- matching the GEMM read swizzle exactly.
__global__ void wconv_kernel(const float* __restrict__ src, short* __restrict__ dst,
                             const int K, const int N, const int nT, const int kT,
                             const int BN) {
  const int tid = threadIdx.x;
  int b = blockIdx.x;
  const int kt = b % kT;
  b /= kT;
  const int nt = b % nT;
  const int slab = b / nT;
  const float* s0 = src + (size_t)slab * K * N + (size_t)(kt * 32) * N + nt * BN;
  short8v* d = (short8v*)(dst + ((size_t)((slab * nT + nt) * kT + kt)) * BN * 32);
  const int upt = BN >> 6;                 // units per thread (1 or 2)
  for (int q = 0; q < upt; ++q) {
    const int uidx = tid + q * 256;
    const int n = uidx >> 2;
    const int u = uidx & 3;
    const int koct = u ^ ((n >> 1) & 3);
    const float* s = s0 + (size_t)(koct * 8) * N + n;
    short8v v;
#pragma unroll
    for (int j = 0; j < 8; ++j) v[j] = f2bf(s[(size_t)j * N]);
    d[uidx] = v;
  }
}

// ================= merged UP: H = bf16( silu(A*B1) * (A*B3) )
// BM=128, BN=64 (dual mats), BK=32, 256 thr, 4 waves in M, wave tile 32x64.
// All staging via global_load_lds from pre-swizzled bf16 weights; depth-3 LDS,
// counted vmcnt(8) -> 2-step latency budget.  4 glds/wave/step.
__launch_bounds__(256, 3)
__global__ void moe_up_k(const short* __restrict__ xg, const short* __restrict__ xb,
                         const short* __restrict__ cw1, const short* __restrict__ cw3,
                         const short* __restrict__ csg, const short* __restrict__ csu,
                         short* __restrict__ hbE, short* __restrict__ hbS,
                         const int* __restrict__ counts, const int* __restrict__ offsets) {
  const int tid = threadIdx.x;
  const int lin = blockIdx.x;
  const short* A; const short* b1tile; const short* b3tile; short* H;
  int N, mtile, ntile, rowbase = 0, cnt = 0x7fffffff;
  bool expert;
  if (lin < 26 * 32 * NEXP) {
    int idx = (lin & 7) * 1664 + (lin >> 3);
    int m = idx & 31;
    int rest = idx >> 5;
    int n = rest % 26;
    int e = rest / 26;
    cnt = counts[e];
    mtile = m * 128;
    if (mtile >= cnt) return;
    rowbase = offsets[e];
    A = xg;
    b1tile = cw1 + ((size_t)((e * 26 + n) * 80)) * 2048;
    b3tile = cw3 + ((size_t)((e * 26 + n) * 80)) * 2048;
    H = hbE; N = IDIM; ntile = n * 64; expert = true;
  } else {
    int s = lin - 26 * 32 * NEXP;   // 0..831
    int n = s % 52;
    int m = s / 52;                 // 0..15
    mtile = m * 128;
    A = xb;
    b1tile = csg + ((size_t)(n * 80)) * 2048;
    b3tile = csu + ((size_t)(n * 80)) * 2048;
    H = hbS; N = ISDIM; ntile = n * 64; expert = false;
  }
  const int K = HDIM;
  const int KT = HDIM / 32;         // 80

  __shared__ short Ab[3][128][32];       // 24 KB, linear
  __shared__ short Bb[3][2][64][32];     // 24 KB, swizzled [n][k]

  f32x4 accG[2][4], accU[2][4];
#pragma unroll
  for (int i = 0; i < 2; ++i)
#pragma unroll
    for (int j = 0; j < 4; ++j) { f32x4 z = {0.f,0.f,0.f,0.f}; accG[i][j] = z; accU[i][j] = z; }

  int gr0, gr1;
  {
    int r0 = tid >> 2, r1 = (tid >> 2) + 64;
    gr0 = expert ? (rowbase + mtile + r0) : (mtile + r0);
    gr1 = expert ? (rowbase + mtile + r1) : (mtile + r1);
    if (gr0 > NPAIR - 1) gr0 = NPAIR - 1;
    if (gr1 > NPAIR - 1) gr1 = NPAIR - 1;
  }
  const int a_ko = (tid & 3) << 3;
  const short* a_src0 = A + (size_t)gr0 * K + a_ko;
  const short* a_src1 = A + (size_t)gr1 * K + a_ko;

#define STAGE_U(kt, buf) do { \
    GLDS16(a_src0 + ((kt) << 5), (short*)Ab[buf] + tid * 8); \
    GLDS16(a_src1 + ((kt) << 5), (short*)Ab[buf] + (tid + 256) * 8); \
    GLDS16(b1tile + (size_t)(kt) * 2048 + tid * 8, (short*)Bb[buf][0] + tid * 8); \
    GLDS16(b3tile + (size_t)(kt) * 2048 + tid * 8, (short*)Bb[buf][1] + tid * 8); \
  } while (0)

  const int lane = tid & 63;
  const int w = tid >> 6;
  const int wm = w * 32;
  const int lrow = lane & 15;
  const int lkg = lane >> 4;

  auto compute = [&](int buf) {
    bf16x8 af[2], bG[4], bU[4];
#pragma unroll
    for (int mf = 0; mf < 2; ++mf)
      af[mf] = *reinterpret_cast<const bf16x8*>(&Ab[buf][wm + mf * 16 + lrow][lkg << 3]);
#pragma unroll
    for (int nf = 0; nf < 4; ++nf) {
      const int n = nf * 16 + lrow;
      const int kg = (lkg ^ ((n >> 1) & 3)) << 3;
      bG[nf] = *reinterpret_cast<const bf16x8*>(&Bb[buf][0][n][kg]);
      bU[nf] = *reinterpret_cast<const bf16x8*>(&Bb[buf][1][n][kg]);
    }
#pragma unroll
    for (int mf = 0; mf < 2; ++mf)
#pragma unroll
      for (int nf = 0; nf < 4; ++nf) {
        accG[mf][nf] = __builtin_amdgcn_mfma_f32_16x16x32_bf16(af[mf], bG[nf], accG[mf][nf], 0, 0, 0);
        accU[mf][nf] = __builtin_amdgcn_mfma_f32_16x16x32_bf16(af[mf], bU[nf], accU[mf][nf], 0, 0, 0);
      }
  };

  STAGE_U(0, 0); STAGE_U(1, 1); STAGE_U(2, 2);
  VMCNT(8);
  PLAIN_BAR();

  int cb = 0;
  for (int i = 0; i < KT; ++i) {
    compute(cb);
    LGKM_BAR();                                 // all waves done reading buf cb
    if (i + 3 < KT)      { STAGE_U(i + 3, cb); VMCNT(8); }
    else if (i + 2 < KT) { VMCNT(4); }
    else if (i + 1 < KT) { VMCNT(0); }
    PLAIN_BAR();                                // buf (i+1)%3 verified ready
    cb = (cb == 2) ? 0 : cb + 1;
  }

  // epilogue: silu(g)*u -> bf16. C/D: col=lane&15, row=(lane>>4)*4+r
#pragma unroll
  for (int mf = 0; mf < 2; ++mf) {
#pragma unroll
    for (int r = 0; r < 4; ++r) {
      const int rt = wm + mf * 16 + ((lane >> 4) << 2) + r;
      if (expert && mtile + rt >= cnt) continue;
      const size_t grow = (size_t)((expert ? rowbase : 0) + mtile + rt);
      const int colb = ntile + lrow;
#pragma unroll
      for (int nf = 0; nf < 4; ++nf) {
        float g = accG[mf][nf][r];
        float u = accU[mf][nf][r];
        H[grow * N + colb + nf * 16] = f2bf(g / (1.f + expf(-g)) * u);
      }
    }
  }
#undef STAGE_U
}

// ================= merged DOWN: Out = A*B.  BM=128, BN=128, BK=32, 256 thr,
// 4 waves (2M x 2N), wave tile 64x64.  Same glds-only depth-3 pipeline.
__launch_bounds__(256, 3)
__global__ void moe_dn_k(const short* __restrict__ hbE, const short* __restrict__ hbS,
                         const short* __restrict__ cw2, const short* __restrict__ csd,
                         float* __restrict__ pairs, float* __restrict__ outb,
                         const int* __restrict__ counts, const int* __restrict__ offsets,
                         const float* __restrict__ wrow) {
  const int tid = threadIdx.x;
  const int lin = blockIdx.x;
  const short* A; const short* btile; float* Out;
  int K, KT, mtile, ntile, rowbase = 0, cnt = 0x7fffffff;
  bool expert;
  if (lin < 20 * 32 * NEXP) {
    int idx = (lin & 7) * 1280 + (lin >> 3);
    int m = idx & 31;
    int rest = idx >> 5;
    int n = rest % 20;
    int e = rest / 20;
    cnt = counts[e];
    mtile = m * 128;
    if (mtile >= cnt) return;
    rowbase = offsets[e];
    A = hbE;
    btile = cw2 + ((size_t)((e * 20 + n) * 52)) * 4096;
    Out = pairs; K = IDIM; KT = IDIM / 32; ntile = n * 128; expert = true;   // KT=52
  } else {
    int s = lin - 20 * 32 * NEXP;   // 0..319
    int n = s % 20;
    int m = s / 20;                 // 0..15
    mtile = m * 128;
    A = hbS;
    btile = csd + ((size_t)(n * 104)) * 4096;
    Out = outb; K = ISDIM; KT = ISDIM / 32; ntile = n * 128;                 // KT=104
    expert = false;
  }

  __shared__ short Ab[3][128][32];   // 24 KB, linear
  __shared__ short Bb[3][128][32];   // 24 KB, swizzled [n][k]

  f32x4 acc[4][4];
#pragma unroll
  for (int i = 0; i < 4; ++i)
#pragma unroll
    for (int j = 0; j < 4; ++j) { f32x4 z = {0.f,0.f,0.f,0.f}; acc[i][j] = z; }

  int gr0, gr1;
  {
    int r0 = tid >> 2, r1 = (tid >> 2) + 64;
    gr0 = expert ? (rowbase + mtile + r0) : (mtile + r0);
    gr1 = expert ? (rowbase + mtile + r1) : (mtile + r1);
    if (gr0 > NPAIR - 1) gr0 = NPAIR - 1;
    if (gr1 > NPAIR - 1) gr1 = NPAIR - 1;
  }
  const int a_ko = (tid & 3) << 3;
  const short* a_src0 = A + (size_t)gr0 * K + a_ko;
  const short* a_src1 = A + (size_t)gr1 * K + a_ko;

#define STAGE_D(kt, buf) do { \
    GLDS16(a_src0 + ((kt) << 5), (short*)Ab[buf] + tid * 8); \
    GLDS16(a_src1 + ((kt) << 5), (short*)Ab[buf] + (tid + 256) * 8); \
    GLDS16(btile + (size_t)(kt) * 4096 + tid * 8, (short*)Bb[buf] + tid * 8); \
    GLDS16(btile + (size_t)(kt) * 4096 + (tid + 256) * 8, (short*)Bb[buf] + (tid + 256) * 8); \
  } while (0)

  const int lane = tid & 63;
  const int w = tid >> 6;
  const int wm = (w >> 1) * 64;
  const int wn = (w & 1) * 64;
  const int lrow = lane & 15;
  const int lkg = lane >> 4;

  auto compute = [&](int buf) {
    bf16x8 af[4], bfv[4];
#pragma unroll
    for (int mf = 0; mf < 4; ++mf)
      af[mf] = *reinterpret_cast<const bf16x8*>(&Ab[buf][wm + mf * 16 + lrow][lkg << 3]);
#pragma unroll
    for (int nf = 0; nf < 4; ++nf) {
      const int n = wn + nf * 16 + lrow;
      const int kg = (lkg ^ ((n >> 1) & 3)) << 3;
      bfv[nf] = *reinterpret_cast<const bf16x8*>(&Bb[buf][n][kg]);
    }
#pragma unroll
    for (int mf = 0; mf < 4; ++mf)
#pragma unroll
      for (int nf = 0; nf < 4; ++nf)
        acc[mf][nf] = __builtin_amdgcn_mfma_f32_16x16x32_bf16(af[mf], bfv[nf], acc[mf][nf], 0, 0, 0);
  };

  STAGE_D(0, 0); STAGE_D(1, 1); STAGE_D(2, 2);
  VMCNT(8);
  PLAIN_BAR();

  int cb = 0;
  for (int i = 0; i < KT; ++i) {
    compute(cb);
    LGKM_BAR();
    if (i + 3 < KT)      { STAGE_D(i + 3, cb); VMCNT(8); }
    else if (i + 2 < KT) { VMCNT(4); }
    else if (i + 1 < KT) { VMCNT(0); }
    PLAIN_BAR();
    cb = (cb == 2) ? 0 : cb + 1;
  }

#pragma unroll
  for (int mf = 0; mf < 4; ++mf) {
#pragma unroll
    for (int r = 0; r < 4; ++r) {
      const int rt = wm + mf * 16 + ((lane >> 4) << 2) + r;
      const int colb = ntile + wn + lrow;
      if (expert) {
        if (mtile + rt < cnt) {
          const int gr = rowbase + mtile + rt;
          const float sc = wrow[gr];
          float* o = Out + (size_t)gr * HDIM + colb;
#pragma unroll
          for (int nf = 0; nf < 4; ++nf) o[nf * 16] = sc * acc[mf][nf][r];
        }
      } else {
        float* o = Out + (size_t)(mtile + rt) * HDIM + colb;
#pragma unroll
        for (int nf = 0; nf < 4; ++nf) o[nf * 16] = acc[mf][nf][r];
      }
    }
  }
#undef STAGE_D
}

// ---------------- final combine: out[t] += pairs[g0] + pairs[g1]
__global__ void combine_kernel(float* __restrict__ out, const float* __restrict__ pairs,
                               const int* __restrict__ pairpos) {
  const int t = blockIdx.x;
  const int g0 = pairpos[t * 2], g1 = pairpos[t * 2 + 1];
  const f32x4* p0 = (const f32x4*)(pairs + (size_t)g0 * HDIM);
  const f32x4* p1 = (const f32x4*)(pairs + (size_t)g1 * HDIM);
  f32x4* o = (f32x4*)(out + (size_t)t * HDIM);
  for (int c = threadIdx.x; c < HDIM / 4; c += 256)
    o[c] = o[c] + p0[c] + p1[c];
}

extern "C" void kernel_launch(void* const* d_in, const int* in_sizes, int n_in,
                              void* d_out, int out_size, void* d_ws, size_t ws_size,
                              hipStream_t stream) {
  const float* x  = (const float*)d_in[0];
  const float* rw = (const float*)d_in[1];
  const float* w1 = (const float*)d_in[2];
  const float* w3 = (const float*)d_in[3];
  const float* w2 = (const float*)d_in[4];
  const float* sg = (const float*)d_in[5];
  const float* su = (const float*)d_in[6];
  const float* sd = (const float*)d_in[7];
  float* out = (float*)d_out;
  (void)in_sizes; (void)n_in; (void)out_size; (void)ws_size;

  char* ws = (char*)d_ws;
  size_t off = 0;
  auto alloc = [&](size_t bytes) -> void* {
    void* p = ws + off;
    off = (off + bytes + 255) & ~(size_t)255;
    return p;
  };
  int*   counts  = (int*)alloc(NEXP * 4);          // @0
  int*   slotc   = (int*)alloc(NEXP * 4);          // @256
  int*   offsets = (int*)alloc(NEXP * 4);
  int*   tidx    = (int*)alloc(NPAIR * 4);
  float* tw      = (float*)alloc(NPAIR * 4);
  float* wrowv   = (float*)alloc(NPAIR * 4);
  int*   pairpos = (int*)alloc(NPAIR * 4);
  short* xb      = (short*)alloc((size_t)TOKENS * HDIM * 2);
  short* xg      = (short*)alloc((size_t)NPAIR * HDIM * 2);
  short* hbE     = (short*)alloc((size_t)NPAIR * IDIM * 2);
  short* hbS     = (short*)alloc((size_t)TOKENS * ISDIM * 2);
  float* pairs   = (float*)alloc((size_t)NPAIR * HDIM * 4);
  // converted-weight regions (phase-reused): A/B hold w1'/w3' then w2' ; S1/S2 hold sg'/su' then sd'
  short* cwA = (short*)alloc((size_t)NEXP * HDIM * IDIM * 2);   // 136.3 MB
  short* cwB = (short*)alloc((size_t)NEXP * HDIM * IDIM * 2);   // 136.3 MB
  short* cwS1 = (short*)alloc((size_t)HDIM * ISDIM * 2);        // 17.0 MB
  short* cwS2 = (short*)alloc((size_t)HDIM * ISDIM * 2);        // 17.0 MB

  hipMemsetAsync(d_ws, 0, 512, stream);  // zero counts + slotc

  router_kernel<<<dim3(TOKENS), dim3(64), 0, stream>>>(x, rw, counts, tidx, tw);
  scan_kernel<<<dim3(1), dim3(64), 0, stream>>>(counts, offsets);
  gather_kernel<<<dim3(TOKENS), dim3(256), 0, stream>>>(x, tidx, tw, offsets, slotc,
                                                        pairpos, wrowv, xb, xg);

  // convert up-phase weights: [K][N] fp32 -> swizzled tile-linear bf16
  wconv_kernel<<<dim3(NEXP * 26 * 80), dim3(256), 0, stream>>>(w1, cwA, HDIM, IDIM, 26, 80, 64);
  wconv_kernel<<<dim3(NEXP * 26 * 80), dim3(256), 0, stream>>>(w3, cwB, HDIM, IDIM, 26, 80, 64);
  wconv_kernel<<<dim3(52 * 80), dim3(256), 0, stream>>>(sg, cwS1, HDIM, ISDIM, 52, 80, 64);
  wconv_kernel<<<dim3(52 * 80), dim3(256), 0, stream>>>(su, cwS2, HDIM, ISDIM, 52, 80, 64);

  // merged up: experts (32m x 26n x 16e = 13312) + shared (832)
  moe_up_k<<<dim3(26 * 32 * NEXP + 832), dim3(256), 0, stream>>>(
      xg, xb, cwA, cwB, cwS1, cwS2, hbE, hbS, counts, offsets);

  // convert down-phase weights into the freed regions
  wconv_kernel<<<dim3(NEXP * 20 * 52), dim3(256), 0, stream>>>(w2, cwA, IDIM, HDIM, 20, 52, 128);
  wconv_kernel<<<dim3(20 * 104), dim3(256), 0, stream>>>(sd, cwS1, ISDIM, HDIM, 20, 104, 128);

  // merged down: experts (32m x 20n x 16e = 10240) + shared (320)
  moe_dn_k<<<dim3(20 * 32 * NEXP + 320), dim3(256), 0, stream>>>(
      hbE, hbS, cwA, cwS1, pairs, out, counts, offsets, wrowv);

  combine_kernel<<<dim3(TOKENS), dim3(256), 0, stream>>>(out, pairs, pairpos);
}

// Round 10
// 782.708 us; speedup vs baseline: 1.1235x; 1.1235x over previous
//
#include <hip/hip_runtime.h>
#include <hip/hip_bf16.h>

#define TOKENS 2048
#define HDIM   2560
#define NEXP   16
#define IDIM   1664
#define ISDIM  3328
#define NPAIR  (TOKENS*2)
#define NPERS  768   // persistent blocks (3/CU x 256)

typedef float  f32x4   __attribute__((ext_vector_type(4)));
typedef __bf16 bf16x8  __attribute__((ext_vector_type(8)));
typedef short  short8v __attribute__((ext_vector_type(8)));

#define GLDS16(g, l) __builtin_amdgcn_global_load_lds( \
    (const __attribute__((address_space(1))) unsigned int*)(g), \
    (__attribute__((address_space(3))) unsigned int*)(l), 16, 0, 0)

#define VMCNT(n) asm volatile("s_waitcnt vmcnt(" #n ")" ::: "memory")
#define LGKM_BAR() do { \
    asm volatile("s_waitcnt lgkmcnt(0)" ::: "memory"); \
    __builtin_amdgcn_sched_barrier(0); \
    __builtin_amdgcn_s_barrier(); \
    __builtin_amdgcn_sched_barrier(0); \
  } while (0)
#define PLAIN_BAR() do { \
    __builtin_amdgcn_sched_barrier(0); \
    __builtin_amdgcn_s_barrier(); \
    __builtin_amdgcn_sched_barrier(0); \
  } while (0)

__device__ __forceinline__ short f2bf(float f) {
  unsigned u = __builtin_bit_cast(unsigned, f);
  u += 0x7FFFu + ((u >> 16) & 1u);          // RNE to bf16
  return (short)(u >> 16);
}

// ---------------- router: fp32 logits, softmax-top2-renorm == sigmoid(l0-l1)
__global__ void router_kernel(const float* __restrict__ x, const float* __restrict__ rw,
                              int* __restrict__ counts, int* __restrict__ tidx,
                              float* __restrict__ tw) {
  const int t = blockIdx.x;
  const int lane = threadIdx.x;
  float acc[NEXP];
#pragma unroll
  for (int e = 0; e < NEXP; ++e) acc[e] = 0.f;
  const float* xr = x + (size_t)t * HDIM;
  for (int k = lane; k < HDIM; k += 64) {
    float xv = xr[k];
#pragma unroll
    for (int e = 0; e < NEXP; ++e) acc[e] += xv * rw[e * HDIM + k];
  }
#pragma unroll
  for (int e = 0; e < NEXP; ++e) {
#pragma unroll
    for (int o = 32; o > 0; o >>= 1) acc[e] += __shfl_down(acc[e], o);
  }
  if (lane == 0) {
    int i0 = 0; float v0 = acc[0];
#pragma unroll
    for (int e = 1; e < NEXP; ++e) if (acc[e] > v0) { v0 = acc[e]; i0 = e; }
    int i1 = -1; float v1 = -3.4e38f;
#pragma unroll
    for (int e = 0; e < NEXP; ++e) if (e != i0 && acc[e] > v1) { v1 = acc[e]; i1 = e; }
    float w0 = 1.f / (1.f + expf(v1 - v0));
    tidx[t * 2] = i0; tidx[t * 2 + 1] = i1;
    tw[t * 2] = w0;   tw[t * 2 + 1] = 1.f - w0;
    atomicAdd(&counts[i0], 1);
    atomicAdd(&counts[i1], 1);
  }
}

// scan + tile-queue metadata: meta[0..16]=panel prefix, meta[17]=upTotal, meta[18]=dnTotal
__global__ void scan_kernel(const int* __restrict__ counts, int* __restrict__ offsets,
                            int* __restrict__ meta) {
  if (threadIdx.x == 0) {
    int a = 0, p = 0;
    for (int e = 0; e < NEXP; ++e) {
      offsets[e] = a;
      meta[e] = p;
      a += counts[e];
      p += (counts[e] + 127) >> 7;     // ceil(cnt/128) panels
    }
    meta[16] = p;
    meta[17] = p * 26 + 832;           // up tiles: expert panels x 26n + shared 16m x 52n
    meta[18] = p * 20 + 320;           // dn tiles: expert panels x 20n + shared 16m x 20n
  }
}

// ---------------- bucket pairs + gather bf16 activations
__global__ void gather_kernel(const float* __restrict__ x, const int* __restrict__ tidx,
                              const float* __restrict__ tw, const int* __restrict__ offsets,
                              int* __restrict__ slotc, int* __restrict__ pairpos,
                              float* __restrict__ wrow, short* __restrict__ xb,
                              short* __restrict__ xg) {
  const int t = blockIdx.x, tid = threadIdx.x;
  __shared__ int grs[2];
  if (tid < 2) {
    int e = tidx[t * 2 + tid];
    int slot = atomicAdd(&slotc[e], 1);
    int g = offsets[e] + slot;
    grs[tid] = g;
    pairpos[t * 2 + tid] = g;
    wrow[g] = tw[t * 2 + tid];
  }
  __syncthreads();
  const int g0 = grs[0], g1 = grs[1];
  const float* xr = x + (size_t)t * HDIM;
#pragma unroll
  for (int i = 0; i < HDIM / 256; ++i) {
    int k = tid + i * 256;
    short v = f2bf(xr[k]);
    xb[(size_t)t * HDIM + k] = v;
    xg[(size_t)g0 * HDIM + k] = v;
    xg[(size_t)g1 * HDIM + k] = v;
  }
}

// ---------------- weight convert: fp32 [K][N] (N-contig) -> bf16 tile-linear,
// pre-swizzled so a linear global_load_lds produces LDS [BN][32] with 16B-unit
// index  n*4 + (koct ^ ((n>>1)&3))  -- matching the GEMM read swizzle exactly.
__global__ void wconv_kernel(const float* __restrict__ src, short* __restrict__ dst,
                             const int K, const int N, const int nT, const int kT,
                             const int BN) {
  const int tid = threadIdx.x;
  int b = blockIdx.x;
  const int kt = b % kT;
  b /= kT;
  const int nt = b % nT;
  const int slab = b / nT;
  const float* s0 = src + (size_t)slab * K * N + (size_t)(kt * 32) * N + nt * BN;
  short8v* d = (short8v*)(dst + ((size_t)((slab * nT + nt) * kT + kt)) * BN * 32);
  const int upt = BN >> 6;                 // units per thread (1 or 2)
  for (int q = 0; q < upt; ++q) {
    const int uidx = tid + q * 256;
    const int n = uidx >> 2;
    const int u = uidx & 3;
    const int koct = u ^ ((n >> 1) & 3);
    const float* s = s0 + (size_t)(koct * 8) * N + n;
    short8v v;
#pragma unroll
    for (int j = 0; j < 8; ++j) v[j] = f2bf(s[(size_t)j * N]);
    d[uidx] = v;
  }
}

// ================= merged UP (persistent): H = bf16( silu(A*B1) * (A*B3) )
// BM=128, BN=64 (dual mats), BK=32, 256 thr.  glds-only depth-3 pipeline.
// Grid-stride over compact ticket space (no dud blocks, no atomics).
__launch_bounds__(256, 3)
__global__ void moe_up_k(const short* __restrict__ xg, const short* __restrict__ xb,
                         const short* __restrict__ cw1, const short* __restrict__ cw3,
                         const short* __restrict__ csg, const short* __restrict__ csu,
                         short* __restrict__ hbE, short* __restrict__ hbS,
                         const int* __restrict__ counts, const int* __restrict__ offsets,
                         const int* __restrict__ meta) {
  const int tid = threadIdx.x;
  __shared__ int spre[17];
  __shared__ short Ab[3][128][32];       // 24 KB, linear
  __shared__ short Bb[3][2][64][32];     // 24 KB, swizzled [n][k]

  if (tid < 17) spre[tid] = meta[tid];
  __syncthreads();
  const int upE = spre[16] * 26;
  const int total = upE + 832;

  const int lane = tid & 63;
  const int w = tid >> 6;
  const int wm = w * 32;
  const int lrow = lane & 15;
  const int lkg = lane >> 4;
  const int a_ko = (tid & 3) << 3;

  for (int ticket = blockIdx.x; ticket < total; ticket += NPERS) {
    const short* A; const short* b1tile; const short* b3tile; short* H;
    int N, mtile, ntile, rowbase = 0, cnt = 0x7fffffff;
    bool expert;
    if (ticket < upE) {
      const int p = ticket / 26;
      const int n = ticket % 26;
      int e = 0;
#pragma unroll
      for (int i = 1; i < 16; ++i) if (p >= spre[i]) e = i;
      const int m = p - spre[e];
      cnt = counts[e];
      rowbase = offsets[e];
      mtile = m * 128;
      A = xg;
      b1tile = cw1 + ((size_t)((e * 26 + n) * 80)) * 2048;
      b3tile = cw3 + ((size_t)((e * 26 + n) * 80)) * 2048;
      H = hbE; N = IDIM; ntile = n * 64; expert = true;
    } else {
      const int s = ticket - upE;     // 0..831
      const int n = s % 52;
      const int m = s / 52;           // 0..15
      mtile = m * 128;
      A = xb;
      b1tile = csg + ((size_t)(n * 80)) * 2048;
      b3tile = csu + ((size_t)(n * 80)) * 2048;
      H = hbS; N = ISDIM; ntile = n * 64; expert = false;
    }
    const int K = HDIM;
    const int KT = HDIM / 32;         // 80

    f32x4 accG[2][4], accU[2][4];
#pragma unroll
    for (int i = 0; i < 2; ++i)
#pragma unroll
      for (int j = 0; j < 4; ++j) { f32x4 z = {0.f,0.f,0.f,0.f}; accG[i][j] = z; accU[i][j] = z; }

    int gr0, gr1;
    {
      int r0 = tid >> 2, r1 = (tid >> 2) + 64;
      gr0 = expert ? (rowbase + mtile + r0) : (mtile + r0);
      gr1 = expert ? (rowbase + mtile + r1) : (mtile + r1);
      if (gr0 > NPAIR - 1) gr0 = NPAIR - 1;
      if (gr1 > NPAIR - 1) gr1 = NPAIR - 1;
    }
    const short* a_src0 = A + (size_t)gr0 * K + a_ko;
    const short* a_src1 = A + (size_t)gr1 * K + a_ko;

#define STAGE_U(kt, buf) do { \
    GLDS16(a_src0 + ((kt) << 5), (short*)Ab[buf] + tid * 8); \
    GLDS16(a_src1 + ((kt) << 5), (short*)Ab[buf] + (tid + 256) * 8); \
    GLDS16(b1tile + (size_t)(kt) * 2048 + tid * 8, (short*)Bb[buf][0] + tid * 8); \
    GLDS16(b3tile + (size_t)(kt) * 2048 + tid * 8, (short*)Bb[buf][1] + tid * 8); \
  } while (0)

    auto compute = [&](int buf) {
      bf16x8 af[2], bG[4], bU[4];
#pragma unroll
      for (int mf = 0; mf < 2; ++mf)
        af[mf] = *reinterpret_cast<const bf16x8*>(&Ab[buf][wm + mf * 16 + lrow][lkg << 3]);
#pragma unroll
      for (int nf = 0; nf < 4; ++nf) {
        const int n = nf * 16 + lrow;
        const int kg = (lkg ^ ((n >> 1) & 3)) << 3;
        bG[nf] = *reinterpret_cast<const bf16x8*>(&Bb[buf][0][n][kg]);
        bU[nf] = *reinterpret_cast<const bf16x8*>(&Bb[buf][1][n][kg]);
      }
#pragma unroll
      for (int mf = 0; mf < 2; ++mf)
#pragma unroll
        for (int nf = 0; nf < 4; ++nf) {
          accG[mf][nf] = __builtin_amdgcn_mfma_f32_16x16x32_bf16(af[mf], bG[nf], accG[mf][nf], 0, 0, 0);
          accU[mf][nf] = __builtin_amdgcn_mfma_f32_16x16x32_bf16(af[mf], bU[nf], accU[mf][nf], 0, 0, 0);
        }
    };

    STAGE_U(0, 0); STAGE_U(1, 1); STAGE_U(2, 2);
    VMCNT(8);
    PLAIN_BAR();

    int cb = 0;
    for (int i = 0; i < KT; ++i) {
      compute(cb);
      LGKM_BAR();
      if (i + 3 < KT)      { STAGE_U(i + 3, cb); VMCNT(8); }
      else if (i + 2 < KT) { VMCNT(4); }
      else if (i + 1 < KT) { VMCNT(0); }
      PLAIN_BAR();
      cb = (cb == 2) ? 0 : cb + 1;
    }

    // epilogue: silu(g)*u -> bf16. C/D: col=lane&15, row=(lane>>4)*4+r
#pragma unroll
    for (int mf = 0; mf < 2; ++mf) {
#pragma unroll
      for (int r = 0; r < 4; ++r) {
        const int rt = wm + mf * 16 + ((lane >> 4) << 2) + r;
        if (expert && mtile + rt >= cnt) continue;
        const size_t grow = (size_t)((expert ? rowbase : 0) + mtile + rt);
        const int colb = ntile + lrow;
#pragma unroll
        for (int nf = 0; nf < 4; ++nf) {
          float g = accG[mf][nf][r];
          float u = accU[mf][nf][r];
          H[grow * N + colb + nf * 16] = f2bf(g / (1.f + expf(-g)) * u);
        }
      }
    }
#undef STAGE_U
  }
}

// ================= merged DOWN (persistent): Out = A*B.  BM=128, BN=128.
// Shared tiles (KT=104) ticketed FIRST so long tiles never start in the tail.
__launch_bounds__(256, 3)
__global__ void moe_dn_k(const short* __restrict__ hbE, const short* __restrict__ hbS,
                         const short* __restrict__ cw2, const short* __restrict__ csd,
                         float* __restrict__ pairs, float* __restrict__ outb,
                         const int* __restrict__ counts, const int* __restrict__ offsets,
                         const float* __restrict__ wrow, const int* __restrict__ meta) {
  const int tid = threadIdx.x;
  __shared__ int spre[17];
  __shared__ short Ab[3][128][32];   // 24 KB, linear
  __shared__ short Bb[3][128][32];   // 24 KB, swizzled [n][k]

  if (tid < 17) spre[tid] = meta[tid];
  __syncthreads();
  const int total = spre[16] * 20 + 320;

  const int lane = tid & 63;
  const int w = tid >> 6;
  const int wm = (w >> 1) * 64;
  const int wn = (w & 1) * 64;
  const int lrow = lane & 15;
  const int lkg = lane >> 4;
  const int a_ko = (tid & 3) << 3;

  for (int ticket = blockIdx.x; ticket < total; ticket += NPERS) {
    const short* A; const short* btile; float* Out;
    int K, KT, mtile, ntile, rowbase = 0, cnt = 0x7fffffff;
    bool expert;
    if (ticket < 320) {               // shared first (long tiles)
      const int n = ticket % 20;
      const int m = ticket / 20;      // 0..15
      mtile = m * 128;
      A = hbS;
      btile = csd + ((size_t)(n * 104)) * 4096;
      Out = outb; K = ISDIM; KT = ISDIM / 32; ntile = n * 128; expert = false; // KT=104
    } else {
      const int te = ticket - 320;
      const int p = te / 20;
      const int n = te % 20;
      int e = 0;
#pragma unroll
      for (int i = 1; i < 16; ++i) if (p >= spre[i]) e = i;
      const int m = p - spre[e];
      cnt = counts[e];
      rowbase = offsets[e];
      mtile = m * 128;
      A = hbE;
      btile = cw2 + ((size_t)((e * 20 + n) * 52)) * 4096;
      Out = pairs; K = IDIM; KT = IDIM / 32; ntile = n * 128; expert = true;   // KT=52
    }

    f32x4 acc[4][4];
#pragma unroll
    for (int i = 0; i < 4; ++i)
#pragma unroll
      for (int j = 0; j < 4; ++j) { f32x4 z = {0.f,0.f,0.f,0.f}; acc[i][j] = z; }

    int gr0, gr1;
    {
      int r0 = tid >> 2, r1 = (tid >> 2) + 64;
      gr0 = expert ? (rowbase + mtile + r0) : (mtile + r0);
      gr1 = expert ? (rowbase + mtile + r1) : (mtile + r1);
      if (gr0 > NPAIR - 1) gr0 = NPAIR - 1;
      if (gr1 > NPAIR - 1) gr1 = NPAIR - 1;
    }
    const short* a_src0 = A + (size_t)gr0 * K + a_ko;
    const short* a_src1 = A + (size_t)gr1 * K + a_ko;

#define STAGE_D(kt, buf) do { \
    GLDS16(a_src0 + ((kt) << 5), (short*)Ab[buf] + tid * 8); \
    GLDS16(a_src1 + ((kt) << 5), (short*)Ab[buf] + (tid + 256) * 8); \
    GLDS16(btile + (size_t)(kt) * 4096 + tid * 8, (short*)Bb[buf] + tid * 8); \
    GLDS16(btile + (size_t)(kt) * 4096 + (tid + 256) * 8, (short*)Bb[buf] + (tid + 256) * 8); \
  } while (0)

    auto compute = [&](int buf) {
      bf16x8 af[4], bfv[4];
#pragma unroll
      for (int mf = 0; mf < 4; ++mf)
        af[mf] = *reinterpret_cast<const bf16x8*>(&Ab[buf][wm + mf * 16 + lrow][lkg << 3]);
#pragma unroll
      for (int nf = 0; nf < 4; ++nf) {
        const int n = wn + nf * 16 + lrow;
        const int kg = (lkg ^ ((n >> 1) & 3)) << 3;
        bfv[nf] = *reinterpret_cast<const bf16x8*>(&Bb[buf][n][kg]);
      }
#pragma unroll
      for (int mf = 0; mf < 4; ++mf)
#pragma unroll
        for (int nf = 0; nf < 4; ++nf)
          acc[mf][nf] = __builtin_amdgcn_mfma_f32_16x16x32_bf16(af[mf], bfv[nf], acc[mf][nf], 0, 0, 0);
    };

    STAGE_D(0, 0); STAGE_D(1, 1); STAGE_D(2, 2);
    VMCNT(8);
    PLAIN_BAR();

    int cb = 0;
    for (int i = 0; i < KT; ++i) {
      compute(cb);
      LGKM_BAR();
      if (i + 3 < KT)      { STAGE_D(i + 3, cb); VMCNT(8); }
      else if (i + 2 < KT) { VMCNT(4); }
      else if (i + 1 < KT) { VMCNT(0); }
      PLAIN_BAR();
      cb = (cb == 2) ? 0 : cb + 1;
    }

#pragma unroll
    for (int mf = 0; mf < 4; ++mf) {
#pragma unroll
      for (int r = 0; r < 4; ++r) {
        const int rt = wm + mf * 16 + ((lane >> 4) << 2) + r;
        const int colb = ntile + wn + lrow;
        if (expert) {
          if (mtile + rt < cnt) {
            const int gr = rowbase + mtile + rt;
            const float sc = wrow[gr];
            float* o = Out + (size_t)gr * HDIM + colb;
#pragma unroll
            for (int nf = 0; nf < 4; ++nf) o[nf * 16] = sc * acc[mf][nf][r];
          }
        } else {
          float* o = Out + (size_t)(mtile + rt) * HDIM + colb;
#pragma unroll
          for (int nf = 0; nf < 4; ++nf) o[nf * 16] = acc[mf][nf][r];
        }
      }
    }
#undef STAGE_D
  }
}

// ---------------- final combine: out[t] += pairs[g0] + pairs[g1]
__global__ void combine_kernel(float* __restrict__ out, const float* __restrict__ pairs,
                               const int* __restrict__ pairpos) {
  const int t = blockIdx.x;
  const int g0 = pairpos[t * 2], g1 = pairpos[t * 2 + 1];
  const f32x4* p0 = (const f32x4*)(pairs + (size_t)g0 * HDIM);
  const f32x4* p1 = (const f32x4*)(pairs + (size_t)g1 * HDIM);
  f32x4* o = (f32x4*)(out + (size_t)t * HDIM);
  for (int c = threadIdx.x; c < HDIM / 4; c += 256)
    o[c] = o[c] + p0[c] + p1[c];
}

extern "C" void kernel_launch(void* const* d_in, const int* in_sizes, int n_in,
                              void* d_out, int out_size, void* d_ws, size_t ws_size,
                              hipStream_t stream) {
  const float* x  = (const float*)d_in[0];
  const float* rw = (const float*)d_in[1];
  const float* w1 = (const float*)d_in[2];
  const float* w3 = (const float*)d_in[3];
  const float* w2 = (const float*)d_in[4];
  const float* sg = (const float*)d_in[5];
  const float* su = (const float*)d_in[6];
  const float* sd = (const float*)d_in[7];
  float* out = (float*)d_out;
  (void)in_sizes; (void)n_in; (void)out_size; (void)ws_size;

  char* ws = (char*)d_ws;
  size_t off = 0;
  auto alloc = [&](size_t bytes) -> void* {
    void* p = ws + off;
    off = (off + bytes + 255) & ~(size_t)255;
    return p;
  };
  int*   counts  = (int*)alloc(NEXP * 4);          // @0
  int*   slotc   = (int*)alloc(NEXP * 4);          // @256
  int*   offsets = (int*)alloc(NEXP * 4);
  int*   meta    = (int*)alloc(32 * 4);
  int*   tidx    = (int*)alloc(NPAIR * 4);
  float* tw      = (float*)alloc(NPAIR * 4);
  float* wrowv   = (float*)alloc(NPAIR * 4);
  int*   pairpos = (int*)alloc(NPAIR * 4);
  short* xb      = (short*)alloc((size_t)TOKENS * HDIM * 2);
  short* xg      = (short*)alloc((size_t)NPAIR * HDIM * 2);
  short* hbE     = (short*)alloc((size_t)NPAIR * IDIM * 2);
  short* hbS     = (short*)alloc((size_t)TOKENS * ISDIM * 2);
  float* pairs   = (float*)alloc((size_t)NPAIR * HDIM * 4);
  // converted-weight regions (phase-reused): A/B hold w1'/w3' then w2'; S1/S2 hold sg'/su' then sd'
  short* cwA  = (short*)alloc((size_t)NEXP * HDIM * IDIM * 2);   // 136.3 MB
  short* cwB  = (short*)alloc((size_t)NEXP * HDIM * IDIM * 2);   // 136.3 MB
  short* cwS1 = (short*)alloc((size_t)HDIM * ISDIM * 2);         // 17.0 MB
  short* cwS2 = (short*)alloc((size_t)HDIM * ISDIM * 2);         // 17.0 MB

  hipMemsetAsync(d_ws, 0, 512, stream);  // zero counts + slotc

  router_kernel<<<dim3(TOKENS), dim3(64), 0, stream>>>(x, rw, counts, tidx, tw);
  scan_kernel<<<dim3(1), dim3(64), 0, stream>>>(counts, offsets, meta);
  gather_kernel<<<dim3(TOKENS), dim3(256), 0, stream>>>(x, tidx, tw, offsets, slotc,
                                                        pairpos, wrowv, xb, xg);

  // convert up-phase weights: [K][N] fp32 -> swizzled tile-linear bf16
  wconv_kernel<<<dim3(NEXP * 26 * 80), dim3(256), 0, stream>>>(w1, cwA, HDIM, IDIM, 26, 80, 64);
  wconv_kernel<<<dim3(NEXP * 26 * 80), dim3(256), 0, stream>>>(w3, cwB, HDIM, IDIM, 26, 80, 64);
  wconv_kernel<<<dim3(52 * 80), dim3(256), 0, stream>>>(sg, cwS1, HDIM, ISDIM, 52, 80, 64);
  wconv_kernel<<<dim3(52 * 80), dim3(256), 0, stream>>>(su, cwS2, HDIM, ISDIM, 52, 80, 64);

  // merged up: persistent 768 blocks over compact ticket space
  moe_up_k<<<dim3(NPERS), dim3(256), 0, stream>>>(
      xg, xb, cwA, cwB, cwS1, cwS2, hbE, hbS, counts, offsets, meta);

  // convert down-phase weights into the freed regions
  wconv_kernel<<<dim3(NEXP * 20 * 52), dim3(256), 0, stream>>>(w2, cwA, IDIM, HDIM, 20, 52, 128);
  wconv_kernel<<<dim3(20 * 104), dim3(256), 0, stream>>>(sd, cwS1, ISDIM, HDIM, 20, 104, 128);

  // merged down: persistent 768 blocks
  moe_dn_k<<<dim3(NPERS), dim3(256), 0, stream>>>(
      hbE, hbS, cwA, cwS1, pairs, out, counts, offsets, wrowv, meta);

  combine_kernel<<<dim3(TOKENS), dim3(256), 0, stream>>>(out, pairs, pairpos);
}